// Round 4
// baseline (971.618 us; speedup 1.0000x reference)
//
#include <hip/hip_runtime.h>
#include <hip/hip_fp16.h>
#include <cstdint>
#include <cstddef>

// DenseCaps dynamic routing, MI355X — R4: materialized fp16 u_hat (R2 design)
// with fixed memory layout.
// B=256, R=2048, NC=10, OUT=16, IN=8, 3 routing iters.
//
// R3 post-mortem: recompute-in-VALU was L1-bound (redundant W reads, 11%
// VALUBusy, 215 us/pass). Reverted to R2 (passed, 270 us), fixing:
//  - U layout b-major -> r-major [R][B][160]: uhat block r writes one
//    contiguous 80 KB region, row-aligned dwordx4 (320 B = 5 full lines).
//  - pass blocks = (b-tile 16) x (r-chunk of 32 routes), grid 1024;
//    per-wave U reads are 1280 B contiguous; v stays in registers.
//
// bB aliases the c-output region of d_out (read+write same thread -> safe).

#define B_   256
#define R_   2048
#define NC_  10

__device__ __forceinline__ float rsum16(float x){
  x += __shfl_xor(x, 1, 16);
  x += __shfl_xor(x, 2, 16);
  x += __shfl_xor(x, 4, 16);
  x += __shfl_xor(x, 8, 16);
  return x;
}
__device__ __forceinline__ float rmax16(float x){
  x = fmaxf(x, __shfl_xor(x, 1, 16));
  x = fmaxf(x, __shfl_xor(x, 2, 16));
  x = fmaxf(x, __shfl_xor(x, 4, 16));
  x = fmaxf(x, __shfl_xor(x, 8, 16));
  return x;
}
__device__ __forceinline__ unsigned pack_f16(float a, float b){
  __half2 h = __floats2half2_rn(a, b);
  return *(unsigned*)&h;
}
__device__ __forceinline__ void unpack8(uint4 d, float* f){
  float2 t;
  t = __half22float2(*(__half2*)&d.x); f[0] = t.x; f[1] = t.y;
  t = __half22float2(*(__half2*)&d.y); f[2] = t.x; f[3] = t.y;
  t = __half22float2(*(__half2*)&d.z); f[4] = t.x; f[5] = t.y;
  t = __half22float2(*(__half2*)&d.w); f[6] = t.x; f[7] = t.y;
}

// ---------- K0: c0 = softmax(b_in) over classes, per route ----------
__global__ __launch_bounds__(256) void c0_kernel(const float* __restrict__ b_in,
                                                 float* __restrict__ c0){
  int r = blockIdx.x * 256 + threadIdx.x;
  if (r >= R_) return;
  float t[NC_];
  float m = -1e30f;
  #pragma unroll
  for (int n = 0; n < NC_; ++n){ t[n] = b_in[r * NC_ + n]; m = fmaxf(m, t[n]); }
  float sum = 0.f;
  #pragma unroll
  for (int n = 0; n < NC_; ++n){ t[n] = __expf(t[n] - m); sum += t[n]; }
  float inv = 1.f / sum;
  #pragma unroll
  for (int n = 0; n < NC_; ++n) c0[r * NC_ + n] = t[n] * inv;
}

// ---------- A: u_hat (fp16) producer, r-major U[r][b][160]. ----------
// One block per route r; thread b computes its 160 outputs; W[r] staged in
// LDS (uniform-address reads -> broadcast). Stores: uint4 at
// base+(r*256+b)*320 + c8*16 — rows are 320 B = exactly 5 lines, block
// region is 80 KB contiguous.
__global__ __launch_bounds__(256) void uhat_kernel(const float* __restrict__ x,
                                                   const float* __restrict__ W,
                                                   uint32_t* __restrict__ U){
  const int r = blockIdx.x;
  __shared__ float Wl[8 * 160];
  {
    const float4* Wg = (const float4*)(W + (size_t)r * 1280);
    float4* Wl4 = (float4*)Wl;
    for (int i = threadIdx.x; i < 320; i += 256) Wl4[i] = Wg[i];
  }
  __syncthreads();
  const int b = threadIdx.x;
  const float4* xp = (const float4*)(x + ((size_t)b * R_ + r) * 8);
  float4 xa = xp[0], xb = xp[1];
  float xr[8] = {xa.x, xa.y, xa.z, xa.w, xb.x, xb.y, xb.z, xb.w};
  uint4* out4 = (uint4*)(U + ((size_t)r * B_ + b) * 80);
  const float4* Wl4 = (const float4*)Wl;
  #pragma unroll 4
  for (int c8 = 0; c8 < 20; ++c8){          // 8 outputs per iteration
    float u[8] = {0.f,0.f,0.f,0.f,0.f,0.f,0.f,0.f};
    #pragma unroll
    for (int i = 0; i < 8; ++i){
      float4 w0 = Wl4[i * 40 + c8 * 2];
      float4 w1 = Wl4[i * 40 + c8 * 2 + 1];
      const float xi = xr[i];
      u[0] = fmaf(xi, w0.x, u[0]); u[1] = fmaf(xi, w0.y, u[1]);
      u[2] = fmaf(xi, w0.z, u[2]); u[3] = fmaf(xi, w0.w, u[3]);
      u[4] = fmaf(xi, w1.x, u[4]); u[5] = fmaf(xi, w1.y, u[5]);
      u[6] = fmaf(xi, w1.z, u[6]); u[7] = fmaf(xi, w1.w, u[7]);
    }
    uint4 pkt;
    pkt.x = pack_f16(u[0], u[1]); pkt.y = pack_f16(u[2], u[3]);
    pkt.z = pack_f16(u[4], u[5]); pkt.w = pack_f16(u[6], u[7]);
    out4[c8] = pkt;
  }
}

// ---------- P<MODE>: fused routing pass ----------
// MODE 0: c = c0 (no agreement)
// MODE 1: bold = b_in, write bnew -> bB
// MODE 2: bold = bB,  write bnew -> bB
// MODE 3: bold = bB,  write c    -> bB (c output region)
// Grid 1024: blockIdx = bt*64 + rc; block = 16 b (bt) x 32 r (rc chunk).
// Thread = (bs 0..15, n 0..15; 10 active classes). v in registers for the
// whole r-loop; per-wave U read = 1280 B contiguous.
template<int MODE>
__global__ __launch_bounds__(256) void pass_kernel(
    const uint32_t* __restrict__ U,    // u_hat fp16, [R][B][160]
    const float*    __restrict__ c0,   // [R][NC]
    const float*    __restrict__ b_in, // [R][NC]
    float*          __restrict__ bB,   // [B][R][NC] (alias of out c-region)
    const float*    __restrict__ v,    // [B][160]
    float*          __restrict__ s)    // [B][160]
{
  const int bt = blockIdx.x >> 6;
  const int rc = blockIdx.x & 63;
  const int n  = threadIdx.x & 15;
  const int bs = threadIdx.x >> 4;
  const int b  = bt * 16 + bs;
  const int nn = (n < NC_) ? n : (NC_ - 1);

  float vreg[16];
  if (MODE != 0){
    const float4* vp = (const float4*)(v + b * 160 + nn * 16);
    float4 v0 = vp[0], v1 = vp[1], v2 = vp[2], v3 = vp[3];
    vreg[0]=v0.x; vreg[1]=v0.y; vreg[2]=v0.z; vreg[3]=v0.w;
    vreg[4]=v1.x; vreg[5]=v1.y; vreg[6]=v1.z; vreg[7]=v1.w;
    vreg[8]=v2.x; vreg[9]=v2.y; vreg[10]=v2.z; vreg[11]=v2.w;
    vreg[12]=v3.x; vreg[13]=v3.y; vreg[14]=v3.z; vreg[15]=v3.w;
  }
  float acc[16];
  #pragma unroll
  for (int o = 0; o < 16; ++o) acc[o] = 0.f;

  const int r0 = rc * 32;
  for (int j = 0; j < 32; ++j){
    const int r = r0 + j;
    const uint4* up = (const uint4*)(U + ((size_t)r * B_ + b) * 80 + nn * 8);
    float uf[16];
    unpack8(up[0], uf);
    unpack8(up[1], uf + 8);

    float c;
    if (MODE == 0){
      c = (n < NC_) ? c0[r * NC_ + nn] : 0.f;
    } else {
      float t = 0.f;
      #pragma unroll
      for (int o = 0; o < 16; ++o) t = fmaf(uf[o], vreg[o], t);
      const size_t row = (size_t)b * R_ + r;
      float bold = (MODE == 1) ? b_in[r * NC_ + nn] : bB[row * NC_ + nn];
      float bnew = (n < NC_) ? (bold + t) : -1e30f;
      float m = rmax16(bnew);
      float e = __expf(bnew - m);            // idle lanes -> 0
      float sum = rsum16(e);
      c = e / sum;
      if (n < NC_){
        if (MODE == 3) bB[row * NC_ + n] = c;      // c output
        else           bB[row * NC_ + n] = bnew;   // logits for next iter
      }
    }
    #pragma unroll
    for (int o = 0; o < 16; ++o) acc[o] = fmaf(c, uf[o], acc[o]);
  }

  // s[b][n][o] += acc  (64-way sharing across rc blocks)
  if (n < NC_){
    float* sp = s + b * 160 + n * 16;
    #pragma unroll
    for (int o = 0; o < 16; ++o) atomicAdd(sp + o, acc[o]);
  }
}

// ---------- Bsq: v = squash(s), optionally zero s for next pass ----------
template<bool FINAL>
__global__ __launch_bounds__(256) void squash_kernel(float* __restrict__ s,
                                                     float* __restrict__ vout){
  int g = blockIdx.x * 256 + threadIdx.x;   // 0..40959; 16 lanes per (b,n) row
  float xv = s[g];
  float ss = rsum16(xv * xv);
  float f = sqrtf(ss) / (1.f + ss + 1e-8f);
  vout[g] = f * xv;
  if (!FINAL) s[g] = 0.f;
}

extern "C" void kernel_launch(void* const* d_in, const int* in_sizes, int n_in,
                              void* d_out, int out_size, void* d_ws, size_t ws_size,
                              hipStream_t stream){
  const float* x    = (const float*)d_in[0];   // [256,2048,8]
  const float* W    = (const float*)d_in[1];   // [2048,8,160]
  const float* b_in = (const float*)d_in[2];   // [2048,10]
  float* out   = (float*)d_out;
  float* out_v = out;                  // 40960 floats
  float* bB    = out + 40960;          // [B][R][NC] — doubles as c output

  char* w = (char*)d_ws;
  uint32_t* U = (uint32_t*)w;                           // 167,772,160 B (fp16, r-major)
  float* s  = (float*)(w + 167772160);                  // 163,840 B
  float* v  = (float*)(w + 167772160 + 163840);         // 163,840 B
  float* c0 = (float*)(w + 167772160 + 2 * 163840);     // 81,920 B

  hipMemsetAsync(s, 0, 40960 * sizeof(float), stream);
  c0_kernel<<<8, 256, 0, stream>>>(b_in, c0);
  uhat_kernel<<<R_, 256, 0, stream>>>(x, W, U);

  pass_kernel<0><<<1024, 256, 0, stream>>>(U, c0, b_in, bB, v, s);
  squash_kernel<false><<<160, 256, 0, stream>>>(s, v);
  pass_kernel<1><<<1024, 256, 0, stream>>>(U, c0, b_in, bB, v, s);
  squash_kernel<false><<<160, 256, 0, stream>>>(s, v);
  pass_kernel<2><<<1024, 256, 0, stream>>>(U, c0, b_in, bB, v, s);
  squash_kernel<false><<<160, 256, 0, stream>>>(s, v);
  pass_kernel<3><<<1024, 256, 0, stream>>>(U, c0, b_in, bB, v, s);
  squash_kernel<true><<<160, 256, 0, stream>>>(s, out_v);
}

// Round 5
// 280.314 us; speedup vs baseline: 3.4662x; 3.4662x over previous
//
#include <hip/hip_runtime.h>
#include <hip/hip_fp16.h>
#include <cstdint>
#include <cstddef>

// DenseCaps dynamic routing, MI355X — R5: register-resident MFMA recompute.
// B=256, R=2048, NC=10, OUT=16, IN=8, 3 routing iters.
//
// History: R2 materialized fp16 u_hat = 270 us (5x168 MB traffic). R3 VALU
// recompute = 888 us (L1-bound on redundant W reads). R4 direct atomics =
// 971 us (2.6M contended atomicAdds serialize). R5: recompute u_hat with
// MFMA per pass — u_hat never leaves registers.
//
// Orientation: u_hatT tile per (r, class n): D = A*B, A = W-slice (M=o(16),
// K=i(8, padded to 32)), B = x (K=i, N=b(16)). C/D layout (HW-verified,
// guide m89): col(lane&15)=b, row(quad*4+reg)=o. So:
//  - agreement t[b,n] = sum_o C*v: 4 in-lane fma + shfl_xor(16)+shfl_xor(32)
//  - softmax over n: per-lane (lane owns one b, all 10 n in regs)
//  - s-partial: acc[n][reg] += c[n]*C[n][reg], LDS-reduced per block, no atomics
// A/B fragments: quad 0 holds the 8 real k's, quads 1-3 are zero (K pad).
//
// Buffers: xh [R][B][8] fp16 (8 MB), wh [R][10][16][8] fp16 = [r][no][i]
// (5.2 MB), bBt [R][10][B] fp32 (21 MB, logits, coalesced per-n rows),
// P [64][B][160] fp32 partial s (10.5 MB). c output [B][R][10] written
// directly in MODE 3.

#define R_   2048
#define NC_  10

typedef _Float16 half8 __attribute__((ext_vector_type(8)));
typedef float   floatx4 __attribute__((ext_vector_type(4)));

__device__ __forceinline__ float rsum16(float x){
  x += __shfl_xor(x, 1, 16);
  x += __shfl_xor(x, 2, 16);
  x += __shfl_xor(x, 4, 16);
  x += __shfl_xor(x, 8, 16);
  return x;
}
// pick element q (0..3) without dynamic register indexing
__device__ __forceinline__ float sel4(float a, float b, float c, float d, int q){
  float x = (q & 1) ? b : a;
  float y = (q & 1) ? d : c;
  return (q & 2) ? y : x;
}

// ---------- pack x -> xh [R][B][8] fp16 ----------
__global__ __launch_bounds__(256) void pack_x_kernel(const float* __restrict__ x,
                                                     _Float16* __restrict__ xh){
  const int r = blockIdx.x, b = threadIdx.x;
  const float4* xp = (const float4*)(x + ((size_t)b * R_ + r) * 8);
  float4 a = xp[0], c = xp[1];
  half8 h;
  h[0]=(_Float16)a.x; h[1]=(_Float16)a.y; h[2]=(_Float16)a.z; h[3]=(_Float16)a.w;
  h[4]=(_Float16)c.x; h[5]=(_Float16)c.y; h[6]=(_Float16)c.z; h[7]=(_Float16)c.w;
  *(half8*)(xh + ((size_t)r * 256 + b) * 8) = h;
}

// ---------- pack W -> wh [R][160][8] fp16  ([r][n*16+o][i]) ----------
__global__ __launch_bounds__(256) void pack_w_kernel(const float* __restrict__ W,
                                                     _Float16* __restrict__ wh){
  const int idx = blockIdx.x * 256 + threadIdx.x;   // r*160 + no
  const int r = idx / 160, no = idx - r * 160;
  half8 h;
  #pragma unroll
  for (int i = 0; i < 8; ++i) h[i] = (_Float16)W[((size_t)r * 8 + i) * 160 + no];
  *(half8*)(wh + (size_t)idx * 8) = h;
}

// ---------- c0 = softmax(b_in) per route ----------
__global__ __launch_bounds__(256) void c0_kernel(const float* __restrict__ b_in,
                                                 float* __restrict__ c0){
  int r = blockIdx.x * 256 + threadIdx.x;
  if (r >= R_) return;
  float t[NC_];
  float m = -1e30f;
  #pragma unroll
  for (int n = 0; n < NC_; ++n){ t[n] = b_in[r * NC_ + n]; m = fmaxf(m, t[n]); }
  float sum = 0.f;
  #pragma unroll
  for (int n = 0; n < NC_; ++n){ t[n] = __expf(t[n] - m); sum += t[n]; }
  float inv = 1.f / sum;
  #pragma unroll
  for (int n = 0; n < NC_; ++n) c0[r * NC_ + n] = t[n] * inv;
}

// ---------- fused MFMA routing pass ----------
// MODE 0: c = c0.  MODE 1: bold = b_in -> bBt.  MODE 2: bold = bBt -> bBt.
// MODE 3: bold = bBt, write c -> c_out (layout [B][R][10]).
// Grid 1024 = 16 b-tiles x 64 r-chunks; block = 4 waves, wave handles 8 r.
template<int MODE>
__global__ __launch_bounds__(256) void pass_kernel(
    const _Float16* __restrict__ xh,    // [R][256][8]
    const _Float16* __restrict__ wh,    // [R][160][8]
    const float*    __restrict__ c0,    // [R][10]
    const float*    __restrict__ b_in,  // [R][10]
    float*          __restrict__ bBt,   // [R][10][256]
    float*          __restrict__ c_out, // [B][R][10]
    const float*    __restrict__ v,     // [B][160]
    float*          __restrict__ P)     // [64][256][160]
{
  const int bt  = blockIdx.x >> 6;
  const int rcb = blockIdx.x & 63;
  const int wv  = threadIdx.x >> 6;
  const int lane = threadIdx.x & 63;
  const int q   = lane >> 4;
  const int col = lane & 15;
  const int b0  = bt * 16;
  const int b   = b0 + col;

  // v fragment: lane needs v[b][n][o=q*4+j]
  float vv[40];
  if (MODE != 0){
    #pragma unroll
    for (int n = 0; n < 10; ++n){
      float4 t4 = *(const float4*)(v + b * 160 + n * 16 + q * 4);
      vv[4*n] = t4.x; vv[4*n+1] = t4.y; vv[4*n+2] = t4.z; vv[4*n+3] = t4.w;
    }
  }
  float acc[40];
  #pragma unroll
  for (int k = 0; k < 40; ++k) acc[k] = 0.f;

  const half8 hz = {0,0,0,0,0,0,0,0};
  const int r0 = rcb * 32 + wv * 8;

  for (int rr = 0; rr < 8; ++rr){
    const int r = r0 + rr;
    half8 bf = hz;
    half8 af[10];
    #pragma unroll
    for (int n = 0; n < 10; ++n) af[n] = hz;
    if (q == 0){
      bf = *(const half8*)(xh + ((size_t)r * 256 + b) * 8);
      #pragma unroll
      for (int n = 0; n < 10; ++n)
        af[n] = *(const half8*)(wh + ((size_t)r * 160 + n * 16 + col) * 8);
    }
    floatx4 C[10];
    #pragma unroll
    for (int n = 0; n < 10; ++n){
      floatx4 z = {0.f, 0.f, 0.f, 0.f};
      C[n] = __builtin_amdgcn_mfma_f32_16x16x32_f16(af[n], bf, z, 0, 0, 0);
    }

    float cc[10];
    if (MODE == 0){
      #pragma unroll
      for (int n = 0; n < 10; ++n) cc[n] = c0[r * 10 + n];
    } else {
      float bn[10];
      #pragma unroll
      for (int n = 0; n < 10; ++n){
        float p =            C[n][0] * vv[4*n];
        p = fmaf(C[n][1], vv[4*n+1], p);
        p = fmaf(C[n][2], vv[4*n+2], p);
        p = fmaf(C[n][3], vv[4*n+3], p);
        p += __shfl_xor(p, 16, 64);
        p += __shfl_xor(p, 32, 64);          // t[b][n] complete in every lane
        float bold = (MODE == 1) ? b_in[r * 10 + n]
                                 : bBt[((size_t)r * 10 + n) * 256 + b];
        bn[n] = bold + p;
      }
      float m = bn[0];
      #pragma unroll
      for (int n = 1; n < 10; ++n) m = fmaxf(m, bn[n]);
      float sum = 0.f;
      #pragma unroll
      for (int n = 0; n < 10; ++n){ cc[n] = __expf(bn[n] - m); sum += cc[n]; }
      float inv = 1.f / sum;
      #pragma unroll
      for (int n = 0; n < 10; ++n) cc[n] *= inv;

      // quad-distributed stores: quad q owns n = q, q+4, (q+8 if q<2)
      if (MODE == 3){
        const size_t base = ((size_t)b * R_ + r) * 10;
        c_out[base + q]     = sel4(cc[0], cc[1], cc[2], cc[3], q);
        c_out[base + q + 4] = sel4(cc[4], cc[5], cc[6], cc[7], q);
        if (q < 2) c_out[base + q + 8] = (q & 1) ? cc[9] : cc[8];
      } else {
        bBt[((size_t)r * 10 + q)     * 256 + b] = sel4(bn[0], bn[1], bn[2], bn[3], q);
        bBt[((size_t)r * 10 + q + 4) * 256 + b] = sel4(bn[4], bn[5], bn[6], bn[7], q);
        if (q < 2) bBt[((size_t)r * 10 + q + 8) * 256 + b] = (q & 1) ? bn[9] : bn[8];
      }
    }
    #pragma unroll
    for (int n = 0; n < 10; ++n){
      acc[4*n]   = fmaf(cc[n], C[n][0], acc[4*n]);
      acc[4*n+1] = fmaf(cc[n], C[n][1], acc[4*n+1]);
      acc[4*n+2] = fmaf(cc[n], C[n][2], acc[4*n+2]);
      acc[4*n+3] = fmaf(cc[n], C[n][3], acc[4*n+3]);
    }
  }

  // block-level reduction of the 4 wave partials (no atomics)
  __shared__ float red[4 * 2560];
  const int off = col * 160 + q * 4;
  #pragma unroll
  for (int n = 0; n < 10; ++n){
    #pragma unroll
    for (int j = 0; j < 4; ++j)
      red[wv * 2560 + off + n * 16 + j] = acc[4*n + j];
  }
  __syncthreads();
  float* Pd = P + ((size_t)rcb * 256 + b0) * 160;
  for (int k = threadIdx.x; k < 2560; k += 256)
    Pd[k] = (red[k] + red[2560 + k]) + (red[5120 + k] + red[7680 + k]);
}

// ---------- reduce 64 partials + squash ----------
template<bool FINAL>
__global__ __launch_bounds__(256) void reduce_squash(const float* __restrict__ P,
                                                     float* __restrict__ vout){
  int g = blockIdx.x * 256 + threadIdx.x;   // 0..40959
  float s0 = 0.f, s1 = 0.f;
  #pragma unroll 8
  for (int j = 0; j < 64; j += 2){
    s0 += P[(size_t)j * 40960 + g];
    s1 += P[(size_t)(j + 1) * 40960 + g];
  }
  float s = s0 + s1;
  float ss = rsum16(s * s);
  float f = sqrtf(ss) / (1.f + ss + 1e-8f);
  vout[g] = f * s;
}

extern "C" void kernel_launch(void* const* d_in, const int* in_sizes, int n_in,
                              void* d_out, int out_size, void* d_ws, size_t ws_size,
                              hipStream_t stream){
  const float* x    = (const float*)d_in[0];   // [256,2048,8]
  const float* W    = (const float*)d_in[1];   // [2048,8,160]
  const float* b_in = (const float*)d_in[2];   // [2048,10]
  float* out   = (float*)d_out;
  float* out_v = out;                  // 40960 floats
  float* c_out = out + 40960;          // [B][R][10]

  char* w = (char*)d_ws;
  _Float16* xh = (_Float16*)w;                         // 8,388,608 B
  _Float16* wh = (_Float16*)(w + 8388608);             // 5,242,880 B
  float* bBt   = (float*)(w + 13631488);               // 20,971,520 B
  float* P     = (float*)(w + 34603008);               // 10,485,760 B
  float* v     = (float*)(w + 45088768);               // 163,840 B
  float* c0    = (float*)(w + 45252608);               // 81,920 B

  pack_x_kernel<<<R_, 256, 0, stream>>>(x, xh);
  pack_w_kernel<<<1280, 256, 0, stream>>>(W, wh);
  c0_kernel<<<8, 256, 0, stream>>>(b_in, c0);

  pass_kernel<0><<<1024, 256, 0, stream>>>(xh, wh, c0, b_in, bBt, c_out, v, P);
  reduce_squash<false><<<160, 256, 0, stream>>>(P, v);
  pass_kernel<1><<<1024, 256, 0, stream>>>(xh, wh, c0, b_in, bBt, c_out, v, P);
  reduce_squash<false><<<160, 256, 0, stream>>>(P, v);
  pass_kernel<2><<<1024, 256, 0, stream>>>(xh, wh, c0, b_in, bBt, c_out, v, P);
  reduce_squash<false><<<160, 256, 0, stream>>>(P, v);
  pass_kernel<3><<<1024, 256, 0, stream>>>(xh, wh, c0, b_in, bBt, c_out, v, P);
  reduce_squash<true><<<160, 256, 0, stream>>>(P, out_v);
}